// Round 8
// baseline (149.586 us; speedup 1.0000x reference)
//
#include <hip/hip_runtime.h>
#include <math.h>

#define N_BOXES 10647
#define NUM_CLASSES 80
#define MAX_BOXES 20
#define IOU_T 0.1f
#define SCORE_T 0.3f

#define NT 1024
#define NWAVES (NT / 64)
#define KP 11    // ceil(N_BOXES / NT): per-thread candidate slots
#define CAPB 4032  // boxes cached in LDS (4032*16 = 64512 B); rest via L1/L2
#define COPY_BLOCKS 176

// Output layout (all float32, concatenated):
//   [0)      boxes copy        N_BOXES*4               = 42588
//   [42588)  scores transposed NUM_CLASSES*N_BOXES     = 851760
//   [894348) nms_final         NUM_CLASSES*MAX_BOXES*3 = 4800
#define TOTAL_COPY (N_BOXES * 4 + NUM_CLASSES * N_BOXES)
#define OUT_OFF_NMS (N_BOXES * 4 + NUM_CLASSES * N_BOXES)

// DESIGN NOTE (R3-R7 post-mortems): the backend caps this kernel's VGPR
// budget at ~64 and REMATERIALIZES per-thread box arrays from memory inside
// the scan loop no matter how they are written (arrays, scalar arrays,
// named scalars: VGPR_Count 56-64, dur ~85us every time). So this version
// makes the memory path explicit and cheap instead: no compaction (positions
// are original indices), 64 KB of LDS holds boxes[0..4032) as an explicit
// cache, the tail streams from L1/L2 coalesced, and only the 11 per-thread
// scores live in registers (low pressure). One barrier per slot via a
// double-buffered reduce array; winner box re-fetched uniformly by all
// threads (LDS or L1 broadcast) instead of owner-publish + second barrier.
#define FOR_K(OP) OP(0) OP(1) OP(2) OP(3) OP(4) OP(5) OP(6) OP(7) OP(8) OP(9) OP(10)

__global__ __launch_bounds__(NT) void yolo_nms_fused(
    const float* __restrict__ boxes, const float* __restrict__ scores,
    float* __restrict__ out) {
    const int tid = threadIdx.x;

    if (blockIdx.x >= NUM_CLASSES) {
        // ---- copy boxes + transpose scores [N,C] -> [C,N] ----
        int idx = (blockIdx.x - NUM_CLASSES) * NT + tid;
        for (; idx < TOTAL_COPY; idx += COPY_BLOCKS * NT) {
            if (idx < N_BOXES * 4) {
                out[idx] = boxes[idx];
            } else {
                int t = idx - N_BOXES * 4;
                int cc = t / N_BOXES;
                int i = t - cc * N_BOXES;
                out[idx] = scores[i * NUM_CLASSES + cc];
            }
        }
        return;
    }

    // ---- per-class greedy NMS ----
    __shared__ float4 s_box4[CAPB];                 // 64512 B box cache
    __shared__ unsigned long long s_rk[2][NWAVES];  // double-buffered reduce
    __shared__ int s_wpos[MAX_BOXES];

    const int c = blockIdx.x;
    const int wave = tid >> 6;
    const int lane = tid & 63;
    const float4* boxes4 = (const float4*)boxes;

    if (tid < MAX_BOXES) s_wpos[tid] = -1;

    // Stage boxes[0..CAPB) into LDS (coalesced float4 loads/stores).
    #pragma unroll
    for (int k = 0; k < 4; ++k) {
        int i = tid + k * NT;
        if (i < CAPB) s_box4[i] = boxes4[i];
    }

    // Per-thread scores (named scalars; ~11 regs, low pressure) + initial
    // argmax. Positions are ORIGINAL indices; strict > with ascending k
    // keeps the lowest index on ties (jnp.argmax first-occurrence).
    float bv = -INFINITY;
    int bp = 0x7FFFFFFF;
#define DECL_K(k) float sc_##k;
    FOR_K(DECL_K)
#undef DECL_K
#define LOADSC_K(k)                                        \
    {                                                      \
        int i = tid + (k)*NT;                              \
        sc_##k = -INFINITY;                                \
        if (i < N_BOXES) {                                 \
            float v = scores[i * NUM_CLASSES + c];         \
            if (v >= SCORE_T) {                            \
                sc_##k = v;                                \
                if (v > bv) { bv = v; bp = i; }            \
            }                                              \
        }                                                  \
    }
    FOR_K(LOADSC_K)
#undef LOADSC_K

    const int out_base = OUT_OFF_NMS + c * MAX_BOXES * 3;

    for (int slot = 0; slot < MAX_BOXES; ++slot) {
        // Pack (score, pos) into a u64 key: valid scores in [0.3, 1) have
        // positive & monotone float bits; u64 max == (max score, tie ->
        // lowest original index). No-candidate key = 0.
        unsigned long long bk = 0;
        if (bv > -INFINITY) {
            bk = ((unsigned long long)__float_as_uint(bv) << 32) |
                 (0xFFFFFFFFu - (unsigned int)bp);
        }
        // ---- wave-level max of packed keys ----
        #pragma unroll
        for (int off = 32; off >= 1; off >>= 1) {
            unsigned long long o =
                (unsigned long long)__shfl_xor((long long)bk, off);
            if (o > bk) bk = o;
        }
        const int par = slot & 1;
        if (lane == 0) s_rk[par][wave] = bk;
        __syncthreads();  // the ONLY barrier per slot (double-buffered s_rk:
                          // slot n+1 writes the other buffer, so no WAR with
                          // this slot's sweep readers)

        // ---- final reduce, redundantly in all threads (broadcast LDS) ----
        unsigned long long f = s_rk[par][0];
        #pragma unroll
        for (int w = 1; w < NWAVES; ++w) {
            unsigned long long o = s_rk[par][w];
            if (o > f) f = o;
        }
        if (f == 0) break;  // uniform: no candidates left

        const int fp = (int)(0xFFFFFFFFu - (unsigned int)f);
        if (tid == 0) s_wpos[slot] = fp;  // read only after final barrier
        if (slot == MAX_BOXES - 1) break;

        // Winner box: uniform fetch (LDS broadcast or single L1 line).
        float4 wb;
        if (fp < CAPB) wb = s_box4[fp];
        else wb = boxes4[fp];
        const float jy1 = wb.x, jx1 = wb.y, jy2 = wb.z, jx2 = wb.w;
        // Same individually-rounded op order as the reference.
        const float area_j =
            __fmul_rn(__fsub_rn(jy2, jy1), __fsub_rn(jx2, jx1));

        // ---- fused suppression + next argmax. Unconditional loads/math
        // (wave64 predication wouldn't save VALU anyway); killing an
        // already-dead candidate is a harmless -inf overwrite.
        bv = -INFINITY;
        bp = 0x7FFFFFFF;
#define SCAN_K(k)                                                         \
        {                                                                 \
            int i = tid + (k)*NT;                                         \
            if (((k) < KP - 1) || (i < N_BOXES)) {                        \
                float4 b;                                                 \
                if ((k) < 3) b = s_box4[i];                               \
                else if ((k) == 3 && i < CAPB) b = s_box4[i];             \
                else b = boxes4[i];                                       \
                float ty = fmaxf(jy1, b.x);                               \
                float tx = fmaxf(jx1, b.y);                               \
                float by = fminf(jy2, b.z);                               \
                float bx = fminf(jx2, b.w);                               \
                float dy = fmaxf(__fsub_rn(by, ty), 0.0f);                \
                float dx = fmaxf(__fsub_rn(bx, tx), 0.0f);                \
                float inter = __fmul_rn(dy, dx);                          \
                float area_i = __fmul_rn(__fsub_rn(b.z, b.x),             \
                                         __fsub_rn(b.w, b.y));            \
                float uni = __fsub_rn(__fadd_rn(area_j, area_i), inter);  \
                float iou = (uni > 0.0f) ? __fdiv_rn(inter, uni) : 0.0f;  \
                bool kill = (iou > IOU_T) || (i == fp);                   \
                if (kill) sc_##k = -INFINITY;                             \
                float v = sc_##k;                                         \
                if (v > bv) { bv = v; bp = i; }                           \
            }                                                             \
        }
        FOR_K(SCAN_K)
#undef SCAN_K
    }

    // ---- emit all output rows once ----
    __syncthreads();
    if (tid < MAX_BOXES) {
        int fp = s_wpos[tid];
        int o = out_base + tid * 3;
        if (fp >= 0) {
            out[o + 0] = 0.0f;
            out[o + 1] = (float)c;
            out[o + 2] = (float)fp;  // positions ARE original indices
        } else {
            out[o + 0] = -1.0f;
            out[o + 1] = -1.0f;
            out[o + 2] = -1.0f;
        }
    }
}

extern "C" void kernel_launch(void* const* d_in, const int* in_sizes, int n_in,
                              void* d_out, int out_size, void* d_ws,
                              size_t ws_size, hipStream_t stream) {
    const float* boxes = (const float*)d_in[0];   // [N,4] fp32
    const float* scores = (const float*)d_in[1];  // [N,C] fp32
    float* out = (float*)d_out;

    yolo_nms_fused<<<NUM_CLASSES + COPY_BLOCKS, NT, 0, stream>>>(boxes, scores,
                                                                 out);
}

// Round 9
// 105.114 us; speedup vs baseline: 1.4231x; 1.4231x over previous
//
#include <hip/hip_runtime.h>
#include <math.h>

#define N_BOXES 10647
#define NUM_CLASSES 80
#define MAX_BOXES 20
#define IOU_T 0.1f
#define SCORE_T 0.3f

#define NT 1024
#define NWAVES (NT / 64)
#define KP 11      // ceil(N_BOXES / NT): per-thread candidate slots
#define WCAP 512   // window capacity (LDS)
#define WSLOTS 8   // WCAP / 64
#define TGT 448    // target window size (expected need ~40; margin >10x)
#define COPY_BLOCKS 176

// Output layout (all float32, concatenated):
//   [0)      boxes copy        N_BOXES*4               = 42588
//   [42588)  scores transposed NUM_CLASSES*N_BOXES     = 851760
//   [894348) nms_final         NUM_CLASSES*MAX_BOXES*3 = 4800
#define TOTAL_COPY (N_BOXES * 4 + NUM_CLASSES * N_BOXES)
#define OUT_OFF_NMS (N_BOXES * 4 + NUM_CLASSES * N_BOXES)

// ALGORITHM NOTE (R1-R8 post-mortems): every "scan all 10647 candidates x20
// slots" variant plateaus at 85-100us (latency-bound on ~150KB/slot/class).
// Greedy NMS == process candidates in (score desc, idx asc) order, keep iff
// IoU<=T vs all kept so far, stop at 20. The live global max always lies in
// the top-score window until the whole window is dead. So: extract a ~448-
// candidate top-score window (histogram threshold), run greedy entirely
// inside it with ONE wave (no block barriers, no global traffic), and keep
// an exact full-scan fallback for window exhaustion / pathological ties.
#define FOR_K(OP) OP(0) OP(1) OP(2) OP(3) OP(4) OP(5) OP(6) OP(7) OP(8) OP(9) OP(10)
#define FOR_J(OP) OP(0) OP(1) OP(2) OP(3) OP(4) OP(5) OP(6) OP(7)

// Reference-exact IoU>T test (individually rounded float32 ops; inter==0 =>
// reference IoU is 0 => not suppressed, divide skipped).
__device__ __forceinline__ bool iou_gt(float jy1, float jx1, float jy2,
                                       float jx2, float area_j, float4 b) {
    float ty = fmaxf(jy1, b.x);
    float tx = fmaxf(jx1, b.y);
    float by = fminf(jy2, b.z);
    float bx = fminf(jx2, b.w);
    float dy = fmaxf(__fsub_rn(by, ty), 0.0f);
    float dx = fmaxf(__fsub_rn(bx, tx), 0.0f);
    float inter = __fmul_rn(dy, dx);
    if (!(inter > 0.0f)) return false;
    float area_i = __fmul_rn(__fsub_rn(b.z, b.x), __fsub_rn(b.w, b.y));
    float uni = __fsub_rn(__fadd_rn(area_j, area_i), inter);
    float iou = (uni > 0.0f) ? __fdiv_rn(inter, uni) : 0.0f;
    return iou > IOU_T;
}

__global__ __launch_bounds__(NT) void yolo_nms_fused(
    const float* __restrict__ boxes, const float* __restrict__ scores,
    float* __restrict__ out) {
    const int tid = threadIdx.x;

    if (blockIdx.x >= NUM_CLASSES) {
        // ---- copy boxes + transpose scores [N,C] -> [C,N] ----
        int idx = (blockIdx.x - NUM_CLASSES) * NT + tid;
        for (; idx < TOTAL_COPY; idx += COPY_BLOCKS * NT) {
            if (idx < N_BOXES * 4) {
                out[idx] = boxes[idx];
            } else {
                int t = idx - N_BOXES * 4;
                int cc = t / N_BOXES;
                int i = t - cc * N_BOXES;
                out[idx] = scores[i * NUM_CLASSES + cc];
            }
        }
        return;
    }

    // ---- per-class NMS ----
    __shared__ int s_hist[2048];                    // 8 KB score-bit histogram
    __shared__ unsigned long long s_k[WCAP];        // 4 KB window keys
    __shared__ float4 s_b4[WCAP];                   // 8 KB window boxes
    __shared__ unsigned long long s_rk[2][NWAVES];  // fallback reduce buffer
    __shared__ int s_out[MAX_BOXES];
    __shared__ int s_selslot[MAX_BOXES];
    __shared__ int s_bstar, s_total, s_cnt, s_nsel;

    const int c = blockIdx.x;
    const int wave = tid >> 6;
    const int lane = tid & 63;
    const float4* boxes4 = (const float4*)boxes;

    // init
    if (tid < MAX_BOXES) s_out[tid] = -1;
    if (tid == 0) { s_cnt = 0; s_nsel = 0; }
    s_hist[tid] = 0;
    s_hist[tid + NT] = 0;
    __syncthreads();

    // ---- Phase A: per-thread keys (named scalars; no allocas) + histogram.
    // key = (score_bits << 32) | (0xFFFFFFFF - idx): u64 max == max score,
    // tie -> lowest index (jnp.argmax first-occurrence). 0 = invalid.
#define DECL_K(k) unsigned long long k_##k = 0;
    FOR_K(DECL_K)
#undef DECL_K
#define BUILD_K(k)                                                     \
    {                                                                  \
        int i = tid + (k)*NT;                                          \
        if (i < N_BOXES) {                                             \
            float v = scores[i * NUM_CLASSES + c];                     \
            if (v >= SCORE_T) {                                        \
                unsigned int vb = __float_as_uint(v);                  \
                k_##k = ((unsigned long long)vb << 32) |               \
                        (0xFFFFFFFFu - (unsigned int)i);               \
                atomicAdd(&s_hist[(vb - 0x3E800000u) >> 13], 1);       \
            }                                                          \
        }                                                              \
    }
    FOR_K(BUILD_K)
#undef BUILD_K
    __syncthreads();

    // ---- Phase B: wave 0 finds threshold bin b* = max bin with
    // suffix-count >= TGT (or 0 if fewer than TGT candidates total).
    if (wave == 0) {
        int lsum = 0;
        #pragma unroll
        for (int bb = 0; bb < 32; ++bb) lsum += s_hist[lane * 32 + bb];
        int S = lsum;  // inclusive suffix over lanes (high lane = high bins)
        #pragma unroll
        for (int off = 1; off < 64; off <<= 1) {
            int up = __shfl_down(S, off);
            if (lane + off < 64) S += up;
        }
        unsigned long long mk = __ballot(S >= TGT);
        if (mk == 0) {
            if (lane == 0) s_bstar = 0;
        } else {
            int L = 63 - __builtin_clzll(mk);
            if (lane == L) {
                int acc = S - lsum;  // suffix above this lane's bins
                int bs = 0;
                for (int bb = L * 32 + 31; bb >= L * 32; --bb) {
                    acc += s_hist[bb];
                    if (acc >= TGT) { bs = bb; break; }
                }
                s_bstar = bs;
            }
        }
        if (lane == 0) s_total = S;  // lane0 suffix == grand total
    }
    __syncthreads();

    const unsigned int tbits = 0x3E800000u + ((unsigned int)s_bstar << 13);

    // ---- Phase C: compact window members (score_bits >= tbits) into LDS.
    // Order-free (keys carry tie-break): per-wave ballot + atomic base.
#define COMPACT_K(k)                                                    \
    {                                                                   \
        bool p = (k_##k != 0) &&                                        \
                 ((unsigned int)(k_##k >> 32) >= tbits);                \
        unsigned long long m = __ballot(p);                             \
        int basew = 0;                                                  \
        if (lane == 0 && m) basew = atomicAdd(&s_cnt, __popcll(m));     \
        basew = __shfl(basew, 0);                                       \
        if (p) {                                                        \
            int pos = basew + __popcll(m & ((1ull << lane) - 1ull));    \
            if (pos < WCAP) {                                           \
                s_k[pos] = k_##k;                                       \
                s_b4[pos] = boxes4[0xFFFFFFFFu - (unsigned int)k_##k];  \
            }                                                           \
        }                                                               \
    }
    FOR_K(COMPACT_K)
#undef COMPACT_K
    __syncthreads();

    const int wcnt = s_cnt;
    const bool overflow = (wcnt > WCAP);  // pathological ties only

    // ---- Phase D: wave-0-only greedy on the window. No block barriers,
    // no global memory. Keys in registers, boxes in LDS.
    if (wave == 0 && !overflow) {
#define DECL_J(j) unsigned long long w_##j = 0;
        FOR_J(DECL_J)
#undef DECL_J
#define LOADW_J(j)                                             \
        { int i = lane + 64 * (j); if (i < wcnt) w_##j = s_k[i]; }
        FOR_J(LOADW_J)
#undef LOADW_J
        int nsel = 0;
        for (int sel = 0; sel < MAX_BOXES; ++sel) {
            unsigned long long bk = 0;
#define MAX_J(j) if (w_##j > bk) bk = w_##j;
            FOR_J(MAX_J)
#undef MAX_J
            #pragma unroll
            for (int off = 32; off >= 1; off >>= 1) {
                unsigned long long o =
                    (unsigned long long)__shfl_xor((long long)bk, off);
                if (o > bk) bk = o;
            }
            if (bk == 0) break;  // window exhausted (wave-uniform)
            // find winner slot (keys unique)
            int ms = -1;
#define FIND_J(j) if (w_##j == bk) ms = lane + 64 * (j);
            FOR_J(FIND_J)
#undef FIND_J
            unsigned long long bal = __ballot(ms >= 0);
            int src = __ffsll((unsigned long long)bal) - 1;
            int winslot = __shfl(ms, src);
            if (lane == 0) {
                s_out[nsel] = (int)(0xFFFFFFFFu - (unsigned int)bk);
                s_selslot[nsel] = winslot;
            }
            float4 wb = s_b4[winslot];  // LDS broadcast
            const float area_j =
                __fmul_rn(__fsub_rn(wb.z, wb.x), __fsub_rn(wb.w, wb.y));
            // kill pass (winner self-kills via IoU=1)
#define KILL_J(j)                                                       \
            if (w_##j != 0) {                                           \
                float4 b = s_b4[lane + 64 * (j)];                       \
                if (iou_gt(wb.x, wb.y, wb.z, wb.w, area_j, b))          \
                    w_##j = 0;                                          \
            }
            FOR_J(KILL_J)
#undef KILL_J
            ++nsel;
        }
        if (lane == 0) s_nsel = nsel;
    }
    __syncthreads();

    // ---- Phase E: exact fallback (window exhausted before 20, or
    // overflow). Never triggers on typical data; required for exactness.
    const int nsel0 = s_nsel;
    const bool needs_more =
        (nsel0 < MAX_BOXES) && (overflow || (wcnt < s_total));
    if (needs_more) {
        // Recompute liveness: alive iff valid, NOT a window member
        // (window all dead unless overflow -> window never ran), and not
        // suppressed by any selected-so-far box.
#define LIVE_K(k)                                                        \
        if (k_##k != 0) {                                                \
            bool dead =                                                  \
                (!overflow &&                                            \
                 ((unsigned int)(k_##k >> 32) >= tbits));                \
            if (!dead && nsel0 > 0) {                                    \
                int i = tid + (k)*NT;                                    \
                float4 bi = boxes4[i];                                   \
                for (int j = 0; j < nsel0; ++j) {                        \
                    float4 sb = s_b4[s_selslot[j]];                      \
                    float aj = __fmul_rn(__fsub_rn(sb.z, sb.x),          \
                                         __fsub_rn(sb.w, sb.y));         \
                    if (iou_gt(sb.x, sb.y, sb.z, sb.w, aj, bi)) {        \
                        dead = true;                                     \
                        break;                                           \
                    }                                                    \
                }                                                        \
            }                                                            \
            if (dead) k_##k = 0;                                         \
        }
        FOR_K(LIVE_K)
#undef LIVE_K
        // Full-scan greedy for the remaining slots (R8-proven structure).
        for (int slot = nsel0; slot < MAX_BOXES; ++slot) {
            unsigned long long bk = 0;
#define MAXK_K(k) if (k_##k > bk) bk = k_##k;
            FOR_K(MAXK_K)
#undef MAXK_K
            #pragma unroll
            for (int off = 32; off >= 1; off >>= 1) {
                unsigned long long o =
                    (unsigned long long)__shfl_xor((long long)bk, off);
                if (o > bk) bk = o;
            }
            const int par = slot & 1;
            if (lane == 0) s_rk[par][wave] = bk;
            __syncthreads();
            unsigned long long f = s_rk[par][0];
            #pragma unroll
            for (int w = 1; w < NWAVES; ++w) {
                unsigned long long o = s_rk[par][w];
                if (o > f) f = o;
            }
            if (f == 0) break;  // uniform
            const int widx = (int)(0xFFFFFFFFu - (unsigned int)f);
            if (tid == 0) s_out[slot] = widx;
            float4 wb = boxes4[widx];  // uniform L1 broadcast
            const float area_j =
                __fmul_rn(__fsub_rn(wb.z, wb.x), __fsub_rn(wb.w, wb.y));
#define SCANE_K(k)                                                      \
            if (k_##k != 0) {                                           \
                int i = tid + (k)*NT;                                   \
                float4 b = boxes4[i];                                   \
                if (i == widx ||                                        \
                    iou_gt(wb.x, wb.y, wb.z, wb.w, area_j, b))          \
                    k_##k = 0;                                          \
            }
            FOR_K(SCANE_K)
#undef SCANE_K
        }
    }

    // ---- emit rows ----
    __syncthreads();
    if (tid < MAX_BOXES) {
        int bi = s_out[tid];
        int o = OUT_OFF_NMS + c * MAX_BOXES * 3 + tid * 3;
        if (bi >= 0) {
            out[o + 0] = 0.0f;
            out[o + 1] = (float)c;
            out[o + 2] = (float)bi;
        } else {
            out[o + 0] = -1.0f;
            out[o + 1] = -1.0f;
            out[o + 2] = -1.0f;
        }
    }
}

extern "C" void kernel_launch(void* const* d_in, const int* in_sizes, int n_in,
                              void* d_out, int out_size, void* d_ws,
                              size_t ws_size, hipStream_t stream) {
    const float* boxes = (const float*)d_in[0];   // [N,4] fp32
    const float* scores = (const float*)d_in[1];  // [N,C] fp32
    float* out = (float*)d_out;

    yolo_nms_fused<<<NUM_CLASSES + COPY_BLOCKS, NT, 0, stream>>>(boxes, scores,
                                                                 out);
}

// Round 10
// 100.404 us; speedup vs baseline: 1.4898x; 1.0469x over previous
//
#include <hip/hip_runtime.h>
#include <math.h>

#define N_BOXES 10647
#define NUM_CLASSES 80
#define MAX_BOXES 20
#define IOU_T 0.1f
#define SCORE_T 0.3f

#define NT 1024
#define NWAVES (NT / 64)
#define KP 11      // ceil(N_BOXES / NT): per-thread candidate slots
#define WCAP 512   // window capacity (LDS)
#define TGT 448    // target window size (expected need ~40; margin >10x)

// Transpose tiling (kernel 1)
#define TROWS 128
#define TBLOCKS 84      // ceil(10647 / 128)
#define CPBLOCKS 6      // boxes-copy blocks
#define K1_BLOCKS (TBLOCKS + CPBLOCKS)

// Output layout (all float32, concatenated):
//   [0)      boxes copy        N_BOXES*4               = 42588
//   [42588)  scores transposed NUM_CLASSES*N_BOXES     = 851760
//   [894348) nms_final         NUM_CLASSES*MAX_BOXES*3 = 4800
#define OUT_OFF_SCORES (N_BOXES * 4)
#define OUT_OFF_NMS (N_BOXES * 4 + NUM_CLASSES * N_BOXES)

// R9 post-mortem: NMS kernel was latency-bound on UNCOALESCED score-column
// reads (stride 320 B -> one 64B line per 4B element; FETCH_SIZE 14MB for
// 3.6MB ideal, VALUBusy 3.4%). Fix: kernel 1 transposes scores into the
// output buffer with both sides coalesced (LDS 128x81 tile); kernel 2 (NMS)
// reads its class column contiguously from that region. Window-greedy
// algorithm (histogram threshold -> ~448-candidate LDS window -> wave0-only
// greedy, exact full-scan fallback) carried over from R9 verified kernel.
#define FOR_K(OP) OP(0) OP(1) OP(2) OP(3) OP(4) OP(5) OP(6) OP(7) OP(8) OP(9) OP(10)
#define FOR_J(OP) OP(0) OP(1) OP(2) OP(3) OP(4) OP(5) OP(6) OP(7)

// Reference-exact IoU>T test (individually rounded float32 ops; inter==0 =>
// reference IoU is 0 => not suppressed, divide skipped).
__device__ __forceinline__ bool iou_gt(float jy1, float jx1, float jy2,
                                       float jx2, float area_j, float4 b) {
    float ty = fmaxf(jy1, b.x);
    float tx = fmaxf(jx1, b.y);
    float by = fminf(jy2, b.z);
    float bx = fminf(jx2, b.w);
    float dy = fmaxf(__fsub_rn(by, ty), 0.0f);
    float dx = fmaxf(__fsub_rn(bx, tx), 0.0f);
    float inter = __fmul_rn(dy, dx);
    if (!(inter > 0.0f)) return false;
    float area_i = __fmul_rn(__fsub_rn(b.z, b.x), __fsub_rn(b.w, b.y));
    float uni = __fsub_rn(__fadd_rn(area_j, area_i), inter);
    float iou = (uni > 0.0f) ? __fdiv_rn(inter, uni) : 0.0f;
    return iou > IOU_T;
}

// ---------------------------------------------------------------------------
// Kernel 1: coalesced transpose of scores [N,C]->[C,N] into out, + boxes copy
// ---------------------------------------------------------------------------
__global__ __launch_bounds__(NT) void transpose_copy_kernel(
    const float* __restrict__ boxes, const float* __restrict__ scores,
    float* __restrict__ out) {
    const int tid = threadIdx.x;
    const int b = blockIdx.x;

    if (b >= TBLOCKS) {
        // ---- boxes copy: 10647 float4s, coalesced both sides ----
        for (int q = (b - TBLOCKS) * NT + tid; q < N_BOXES;
             q += CPBLOCKS * NT) {
            ((float4*)out)[q] = ((const float4*)boxes)[q];
        }
        return;
    }

    // ---- one 128-row x 80-col tile ----
    __shared__ float lds[TROWS * 81];  // [r][c], pad 81 -> conflict-free
    const int r0 = b * TROWS;
    const int nr = min(TROWS, N_BOXES - r0);

    // Read: contiguous chunk scores[r0*80 .. (r0+nr)*80), float4 loads.
    const int nq = nr * 20;  // 80 floats/row = 20 float4/row
    for (int q = tid; q < nq; q += NT) {
        const int r = q / 20;
        const int c4 = (q - r * 20) * 4;
        float4 v = *(const float4*)(scores + (r0 + r) * NUM_CLASSES + c4);
        float* dst = &lds[r * 81 + c4];
        dst[0] = v.x;
        dst[1] = v.y;
        dst[2] = v.z;
        dst[3] = v.w;
    }
    __syncthreads();

    // Write: for each class, 128 consecutive elements of the [C,N] column.
    const int r = tid & (TROWS - 1);
    const int chi = tid >> 7;  // 0..7
    if (r < nr) {
        #pragma unroll
        for (int p = 0; p < 10; ++p) {
            const int c = p * 8 + chi;
            out[OUT_OFF_SCORES + c * N_BOXES + r0 + r] = lds[r * 81 + c];
        }
    }
}

// ---------------------------------------------------------------------------
// Kernel 2: per-class NMS (reads coalesced transposed scores from out)
// ---------------------------------------------------------------------------
__global__ __launch_bounds__(NT) void nms_kernel(
    const float* __restrict__ boxes, float* __restrict__ out) {
    const int tid = threadIdx.x;
    const int c = blockIdx.x;
    const int wave = tid >> 6;
    const int lane = tid & 63;
    const float4* boxes4 = (const float4*)boxes;
    const float* col = out + OUT_OFF_SCORES + c * N_BOXES;  // contiguous

    __shared__ int s_hist[2048];                    // 8 KB
    __shared__ unsigned long long s_k[WCAP];        // 4 KB window keys
    __shared__ float4 s_b4[WCAP];                   // 8 KB window boxes
    __shared__ unsigned long long s_rk[2][NWAVES];  // fallback reduce
    __shared__ int s_out[MAX_BOXES];
    __shared__ int s_selslot[MAX_BOXES];
    __shared__ int s_bstar, s_total, s_cnt, s_nsel;

    if (tid < MAX_BOXES) s_out[tid] = -1;
    if (tid == 0) { s_cnt = 0; s_nsel = 0; }
    s_hist[tid] = 0;
    s_hist[tid + NT] = 0;
    __syncthreads();

    // ---- Phase A: coalesced column read -> keys + histogram.
    // key = (score_bits << 32) | (0xFFFFFFFF - idx): u64 max == max score,
    // tie -> lowest index (jnp.argmax first-occurrence). 0 = invalid.
#define DECL_K(k) unsigned long long k_##k = 0;
    FOR_K(DECL_K)
#undef DECL_K
#define BUILD_K(k)                                                     \
    {                                                                  \
        int i = tid + (k)*NT;                                          \
        if (i < N_BOXES) {                                             \
            float v = col[i];                                          \
            if (v >= SCORE_T) {                                        \
                unsigned int vb = __float_as_uint(v);                  \
                k_##k = ((unsigned long long)vb << 32) |               \
                        (0xFFFFFFFFu - (unsigned int)i);               \
                atomicAdd(&s_hist[(vb - 0x3E800000u) >> 13], 1);       \
            }                                                          \
        }                                                              \
    }
    FOR_K(BUILD_K)
#undef BUILD_K
    __syncthreads();

    // ---- Phase B (wave 0, fully parallel): b* = max bin with
    // suffix-count >= TGT (0 if total < TGT).
    if (wave == 0) {
        int lsum = 0;
        #pragma unroll
        for (int t = 0; t < 32; ++t) {
            int bb = (t + lane) & 31;  // rotate -> conflict-free banks
            lsum += s_hist[lane * 32 + bb];
        }
        int S = lsum;  // inclusive suffix over lanes (lane l: bins >= l*32)
        #pragma unroll
        for (int off = 1; off < 64; off <<= 1) {
            int up = __shfl_down(S, off);
            if (lane + off < 64) S += up;
        }
        unsigned long long mk = __ballot(S >= TGT);
        int bstar = 0;
        if (mk != 0) {
            const int L = 63 - __builtin_clzll(mk);
            const int S_L = __shfl(S, L);
            const int lsum_L = __shfl(lsum, L);
            const int S_above = S_L - lsum_L;  // suffix above lane L's bins
            // lanes 0..31 hold lane L's bins; suffix within via shuffles
            int h = (lane < 32) ? s_hist[L * 32 + lane] : 0;
            int sfx = h;
            #pragma unroll
            for (int off = 1; off < 64; off <<= 1) {
                int up = __shfl_down(sfx, off);
                if (lane + off < 64) sfx += up;
            }
            unsigned long long sel = __ballot(sfx + S_above >= TGT);
            // nonempty: j=0 gives S_L >= TGT
            bstar = L * 32 + (63 - __builtin_clzll(sel));
        }
        if (lane == 0) {
            s_bstar = bstar;
            s_total = S;  // lane0 inclusive suffix == grand total
        }
    }
    __syncthreads();

    const unsigned int tbits = 0x3E800000u + ((unsigned int)s_bstar << 13);

    // ---- Phase C: compact window (score_bits >= tbits) into LDS ----
#define COMPACT_K(k)                                                    \
    {                                                                   \
        bool p = (k_##k != 0) &&                                        \
                 ((unsigned int)(k_##k >> 32) >= tbits);                \
        unsigned long long m = __ballot(p);                             \
        int basew = 0;                                                  \
        if (lane == 0 && m) basew = atomicAdd(&s_cnt, __popcll(m));     \
        basew = __shfl(basew, 0);                                       \
        if (p) {                                                        \
            int pos = basew + __popcll(m & ((1ull << lane) - 1ull));    \
            if (pos < WCAP) {                                           \
                s_k[pos] = k_##k;                                       \
                s_b4[pos] = boxes4[0xFFFFFFFFu - (unsigned int)k_##k];  \
            }                                                           \
        }                                                               \
    }
    FOR_K(COMPACT_K)
#undef COMPACT_K
    __syncthreads();

    const int wcnt = s_cnt;
    const bool overflow = (wcnt > WCAP);  // pathological ties only

    // ---- Phase D: wave-0-only greedy on the window ----
    if (wave == 0 && !overflow) {
#define DECL_J(j) unsigned long long w_##j = 0;
        FOR_J(DECL_J)
#undef DECL_J
#define LOADW_J(j)                                             \
        { int i = lane + 64 * (j); if (i < wcnt) w_##j = s_k[i]; }
        FOR_J(LOADW_J)
#undef LOADW_J
        int nsel = 0;
        for (int sel = 0; sel < MAX_BOXES; ++sel) {
            unsigned long long bk = 0;
#define MAX_J(j) if (w_##j > bk) bk = w_##j;
            FOR_J(MAX_J)
#undef MAX_J
            #pragma unroll
            for (int off = 32; off >= 1; off >>= 1) {
                unsigned long long o =
                    (unsigned long long)__shfl_xor((long long)bk, off);
                if (o > bk) bk = o;
            }
            if (bk == 0) break;  // window exhausted (wave-uniform)
            int ms = -1;
#define FIND_J(j) if (w_##j == bk) ms = lane + 64 * (j);
            FOR_J(FIND_J)
#undef FIND_J
            unsigned long long bal = __ballot(ms >= 0);
            int src = __ffsll((unsigned long long)bal) - 1;
            int winslot = __shfl(ms, src);
            if (lane == 0) {
                s_out[nsel] = (int)(0xFFFFFFFFu - (unsigned int)bk);
                s_selslot[nsel] = winslot;
            }
            float4 wb = s_b4[winslot];  // LDS broadcast
            const float area_j =
                __fmul_rn(__fsub_rn(wb.z, wb.x), __fsub_rn(wb.w, wb.y));
#define KILL_J(j)                                                       \
            if (w_##j != 0) {                                           \
                float4 b = s_b4[lane + 64 * (j)];                       \
                if (iou_gt(wb.x, wb.y, wb.z, wb.w, area_j, b))          \
                    w_##j = 0;                                          \
            }
            FOR_J(KILL_J)
#undef KILL_J
            ++nsel;
        }
        if (lane == 0) s_nsel = nsel;
    }
    __syncthreads();

    // ---- Phase E: exact fallback (window exhausted early / overflow) ----
    const int nsel0 = s_nsel;
    const bool needs_more =
        (nsel0 < MAX_BOXES) && (overflow || (wcnt < s_total));
    if (needs_more) {
#define LIVE_K(k)                                                        \
        if (k_##k != 0) {                                                \
            bool dead =                                                  \
                (!overflow &&                                            \
                 ((unsigned int)(k_##k >> 32) >= tbits));                \
            if (!dead && nsel0 > 0) {                                    \
                int i = tid + (k)*NT;                                    \
                float4 bi = boxes4[i];                                   \
                for (int j = 0; j < nsel0; ++j) {                        \
                    float4 sb = s_b4[s_selslot[j]];                      \
                    float aj = __fmul_rn(__fsub_rn(sb.z, sb.x),          \
                                         __fsub_rn(sb.w, sb.y));         \
                    if (iou_gt(sb.x, sb.y, sb.z, sb.w, aj, bi)) {        \
                        dead = true;                                     \
                        break;                                           \
                    }                                                    \
                }                                                        \
            }                                                            \
            if (dead) k_##k = 0;                                         \
        }
        FOR_K(LIVE_K)
#undef LIVE_K
        for (int slot = nsel0; slot < MAX_BOXES; ++slot) {
            unsigned long long bk = 0;
#define MAXK_K(k) if (k_##k > bk) bk = k_##k;
            FOR_K(MAXK_K)
#undef MAXK_K
            #pragma unroll
            for (int off = 32; off >= 1; off >>= 1) {
                unsigned long long o =
                    (unsigned long long)__shfl_xor((long long)bk, off);
                if (o > bk) bk = o;
            }
            const int par = slot & 1;
            if (lane == 0) s_rk[par][wave] = bk;
            __syncthreads();
            unsigned long long f = s_rk[par][0];
            #pragma unroll
            for (int w = 1; w < NWAVES; ++w) {
                unsigned long long o = s_rk[par][w];
                if (o > f) f = o;
            }
            if (f == 0) break;  // uniform
            const int widx = (int)(0xFFFFFFFFu - (unsigned int)f);
            if (tid == 0) s_out[slot] = widx;
            float4 wb = boxes4[widx];  // uniform L1 broadcast
            const float area_j =
                __fmul_rn(__fsub_rn(wb.z, wb.x), __fsub_rn(wb.w, wb.y));
#define SCANE_K(k)                                                      \
            if (k_##k != 0) {                                           \
                int i = tid + (k)*NT;                                   \
                float4 b = boxes4[i];                                   \
                if (i == widx ||                                        \
                    iou_gt(wb.x, wb.y, wb.z, wb.w, area_j, b))          \
                    k_##k = 0;                                          \
            }
            FOR_K(SCANE_K)
#undef SCANE_K
        }
    }

    // ---- emit rows ----
    __syncthreads();
    if (tid < MAX_BOXES) {
        int bi = s_out[tid];
        int o = OUT_OFF_NMS + c * MAX_BOXES * 3 + tid * 3;
        if (bi >= 0) {
            out[o + 0] = 0.0f;
            out[o + 1] = (float)c;
            out[o + 2] = (float)bi;
        } else {
            out[o + 0] = -1.0f;
            out[o + 1] = -1.0f;
            out[o + 2] = -1.0f;
        }
    }
}

extern "C" void kernel_launch(void* const* d_in, const int* in_sizes, int n_in,
                              void* d_out, int out_size, void* d_ws,
                              size_t ws_size, hipStream_t stream) {
    const float* boxes = (const float*)d_in[0];   // [N,4] fp32
    const float* scores = (const float*)d_in[1];  // [N,C] fp32
    float* out = (float*)d_out;

    // Launch 1: coalesced transpose (+ boxes copy) into out.
    transpose_copy_kernel<<<K1_BLOCKS, NT, 0, stream>>>(boxes, scores, out);
    // Launch 2: NMS reads the transposed columns contiguously.
    nms_kernel<<<NUM_CLASSES, NT, 0, stream>>>(boxes, out);
}